// Round 20
// baseline (47.188 us; speedup 1.0000x reference)
//
#include <hip/hip_runtime.h>
#include <hip/hip_bf16.h>
#include <cstdint>
#include <cstddef>

typedef __attribute__((ext_vector_type(8))) short bf16x8;
typedef __attribute__((ext_vector_type(4))) float f32x4;

__device__ __forceinline__ unsigned short f2bf(float f) {
  union { float f; unsigned u; } v; v.f = f;
  unsigned r = v.u + 0x7FFFu + ((v.u >> 16) & 1u);
  return (unsigned short)(r >> 16);
}

__device__ __forceinline__ float bf2f(unsigned short h) {
  union { float f; unsigned u; } c; c.u = ((unsigned)h) << 16;
  return c.f;
}

__device__ __forceinline__ void gload_lds16(const void* g, void* l) {
  __builtin_amdgcn_global_load_lds(
      (const __attribute__((address_space(1))) unsigned int*)g,
      (__attribute__((address_space(3))) unsigned int*)l, 16, 0, 0);
}

// ---------------------------------------------------------------------------
// K01 (R17-proven): 256 blocks x 1024 thr. x-phase at BW floor (~10us).
// W written FRAG-MAJOR: 1KB record per 16x32 A-frag; lane l's 16B at
// record*1024 + l*16 = A[cls=cf*16+(l&15)][k=kf*32+(l>>4)*8 ..+8).
// Record id = (cls/16)*32 + (k/32). cls-1000 slots zeroed here, overwritten
// by k2 with bf16(s).
// ---------------------------------------------------------------------------
__global__ __launch_bounds__(1024) void k01_prep(const float* __restrict__ W,
                                                 unsigned short* __restrict__ wtf,
                                                 const float* __restrict__ x,
                                                 unsigned short* __restrict__ xbf,
                                                 float* __restrict__ rnorm,
                                                 float* __restrict__ sp) {
  __shared__ __align__(16) char sm[83968];  // sblk 64KB @0 | tile2 18432B @65536
  int tid = threadIdx.x;
  int b = blockIdx.x;
  int lane = tid & 63;
  int wid = tid >> 6;  // 0..15

  int k0 = (b & 15) * 64;
  int c0 = (b >> 4) * 64;
  int tx = tid & 63;
  int ty = tid >> 6;
  float wreg[4];
#pragma unroll
  for (int i = 0; i < 4; ++i) {
    int c = c0 + tx;
    wreg[i] = (c < 1000) ? W[(size_t)(k0 + i * 16 + ty) * 1000 + c] : 0.f;
  }

  {
    float (*sblk)[1024] = (float(*)[1024])sm;
    int row0 = b * 32 + wid * 2;
    const float4* xr0 = (const float4*)(x + (size_t)row0 * 1024);
    const float4* xr1 = (const float4*)(x + (size_t)(row0 + 1) * 1024);
    float4 v[2][4];
#pragma unroll
    for (int j = 0; j < 4; ++j) v[0][j] = xr0[lane + j * 64];
#pragma unroll
    for (int j = 0; j < 4; ++j) v[1][j] = xr1[lane + j * 64];
    float ss0 = 0.f, ss1 = 0.f;
#pragma unroll
    for (int j = 0; j < 4; ++j) {
      ss0 += v[0][j].x * v[0][j].x + v[0][j].y * v[0][j].y +
             v[0][j].z * v[0][j].z + v[0][j].w * v[0][j].w;
      ss1 += v[1][j].x * v[1][j].x + v[1][j].y * v[1][j].y +
             v[1][j].z * v[1][j].z + v[1][j].w * v[1][j].w;
    }
#pragma unroll
    for (int m = 1; m < 64; m <<= 1) {
      ss0 += __shfl_xor(ss0, m);
      ss1 += __shfl_xor(ss1, m);
    }
    float rn0 = 1.f / fmaxf(sqrtf(ss0), 1e-8f);
    float rn1 = 1.f / fmaxf(sqrtf(ss1), 1e-8f);
    if (lane == 0) {
      rnorm[row0] = rn0;
      rnorm[row0 + 1] = rn1;
    }
    float4 sacc[4];
#pragma unroll
    for (int j = 0; j < 4; ++j) {
      ushort4 h0, h1;
      h0.x = f2bf(v[0][j].x); h0.y = f2bf(v[0][j].y);
      h0.z = f2bf(v[0][j].z); h0.w = f2bf(v[0][j].w);
      h1.x = f2bf(v[1][j].x); h1.y = f2bf(v[1][j].y);
      h1.z = f2bf(v[1][j].z); h1.w = f2bf(v[1][j].w);
      ((ushort4*)(xbf + (size_t)row0 * 1024))[lane + j * 64] = h0;
      ((ushort4*)(xbf + (size_t)(row0 + 1) * 1024))[lane + j * 64] = h1;
      sacc[j].x = v[0][j].x * rn0 + v[1][j].x * rn1;
      sacc[j].y = v[0][j].y * rn0 + v[1][j].y * rn1;
      sacc[j].z = v[0][j].z * rn0 + v[1][j].z * rn1;
      sacc[j].w = v[0][j].w * rn0 + v[1][j].w * rn1;
    }
#pragma unroll
    for (int j = 0; j < 4; ++j) ((float4*)sblk[wid])[j * 64 + lane] = sacc[j];
    __syncthreads();
    float acc = 0.f;
#pragma unroll
    for (int w = 0; w < 16; ++w) acc += sblk[w][tid];
    sp[(size_t)b * 1024 + tid] = acc;
  }

  {
    float (*tile2)[72] = (float(*)[72])(sm + 65536);
#pragma unroll
    for (int i = 0; i < 4; ++i) tile2[tx][i * 16 + ty] = wreg[i];
    __syncthreads();
    if (tid < 512) {
      int fi = tid >> 6;   // 0..7: cf = fi>>1, kf = fi&1
      int l = tid & 63;
      int cf = fi >> 1;
      int kf = fi & 1;
      int r2 = cf * 16 + (l & 15);
      int c2 = kf * 32 + (l >> 4) * 8;
      float4 va = *(const float4*)&tile2[r2][c2];
      float4 vb = *(const float4*)&tile2[r2][c2 + 4];
      uint4 o;
      o.x = (unsigned)f2bf(va.x) | ((unsigned)f2bf(va.y) << 16);
      o.y = (unsigned)f2bf(va.z) | ((unsigned)f2bf(va.w) << 16);
      o.z = (unsigned)f2bf(vb.x) | ((unsigned)f2bf(vb.y) << 16);
      o.w = (unsigned)f2bf(vb.z) | ((unsigned)f2bf(vb.w) << 16);
      size_t fg = (size_t)(c0 / 16 + cf) * 32 + (k0 / 32 + kf);
      *(uint4*)((char*)wtf + fg * 1024 + (size_t)l * 16) = o;
    }
  }
}

// ---------------------------------------------------------------------------
// K2: reduce sp -> s AND scatter bf16(s) into the cls-1000 frag-major slots
// (group 62, within-frag row 8): wtf[(62*32 + d/32)*512 + l*8 + (d&7)] with
// l = ((d&31)>>3)*16 + 8.
// ---------------------------------------------------------------------------
__global__ __launch_bounds__(256) void k2_sred(const float* __restrict__ sp,
                                               float* __restrict__ s,
                                               unsigned short* __restrict__ wtf) {
  __shared__ float red[4][64];
  int t = threadIdx.x;
  int dd = t & 63;
  int g = t >> 6;
  int d = blockIdx.x * 64 + dd;
  float acc = 0.f;
#pragma unroll 8
  for (int b = g * 64; b < g * 64 + 64; ++b) acc += sp[(size_t)b * 1024 + d];
  red[g][dd] = acc;
  __syncthreads();
  if (g == 0) {
    float sv = red[0][dd] + red[1][dd] + red[2][dd] + red[3][dd];
    s[d] = sv;
    int kf = d >> 5;
    int j = d & 31;
    int l = ((j >> 3) << 4) | 8;
    wtf[((size_t)62 * 32 + kf) * 512 + (size_t)l * 8 + (j & 7)] = f2bf(sv);
  }
}

// ---------------------------------------------------------------------------
// K3: GEMM + softmax partials. A-frags from frag-major wtf via REGISTER
// DOUBLE-BUFFER prefetched one tile ahead (fixes R17's unprefetched regression)
// -- no A LDS traffic. B in quad-buffered LDS (4 x 32KB, static bases via
// 4-tile unroll), depth-2 staging, counted vmcnt(12) (leaves next tile's
// 8 a-loads + 4 STB in flight). 128 cls x 256 rows, 512 thr, XCD-aligned
// cb=b>>5 / rb=b&31. Class-1000 extraction as R19.
// ---------------------------------------------------------------------------
__global__ __launch_bounds__(512) void k3_gemm(const unsigned short* __restrict__ xbf,
                                               const unsigned short* __restrict__ wtf,
                                               const float* __restrict__ bias,
                                               float* __restrict__ pm,
                                               float* __restrict__ pz,
                                               float* __restrict__ ps,
                                               float* __restrict__ pd) {
  __shared__ __align__(16) char lds[131072];  // B quad-buffer 4 x 32KB

  int tid = threadIdx.x;
  int lane = tid & 63;
  int wid = tid >> 6;  // 0..7
  int wc = wid & 1;
  int wr = wid >> 1;
  int cb = blockIdx.x >> 5;
  int rb = blockIdx.x & 31;
  int C0 = cb * 128;
  int R0 = rb * 256;

  float bv[4][4];
#pragma unroll
  for (int mf = 0; mf < 4; ++mf)
#pragma unroll
    for (int q = 0; q < 4; ++q) {
      int cls_g = C0 + wc * 64 + mf * 16 + (lane >> 4) * 4 + q;
      bv[mf][q] = (cls_g < 1000) ? bias[cls_g] : ((cls_g == 1000) ? 0.f : -1e30f);
    }
  f32x4 acc[4][4];
#pragma unroll
  for (int mf = 0; mf < 4; ++mf)
#pragma unroll
    for (int nf = 0; nf < 4; ++nf)
#pragma unroll
      for (int q = 0; q < 4; ++q) acc[mf][nf][q] = bv[mf][q];

  const char* gB = (const char*)(xbf + (size_t)R0 * 1024);
  int gswz = ((tid & 7) ^ ((tid >> 3) & 7)) << 4;

  auto stageB = [&](int kt, char* lB) {
#pragma unroll
    for (int r = 0; r < 4; ++r) {
      size_t row = r * 64 + (tid >> 3);
      gload_lds16(gB + row * 2048 + kt * 128 + gswz, lB + r * 8192 + wid * 1024);
    }
  };

  // wave's A-frag base: cls-groups cb*8 + wc*4 + mf, k-frag = t*2 + ks
  const char* gAf = (const char*)wtf +
                    ((size_t)(cb * 8 + wc * 4) * 32) * 1024 + (size_t)lane * 16;
  bf16x8 aA[4][2], aB[4][2];
  auto loadA = [&](bf16x8(&dst)[4][2], int t) {
#pragma unroll
    for (int mf = 0; mf < 4; ++mf)
#pragma unroll
      for (int ks = 0; ks < 2; ++ks)
        dst[mf][ks] = *(const bf16x8*)(gAf + (size_t)(mf * 32 + t * 2 + ks) * 1024);
  };

  int rsw = (lane & 7) << 4;
  int kcol = (lane >> 4) * 16;
  auto comp = [&](const char* B, bf16x8(&a)[4][2]) {
    bf16x8 bbf[4][2];
#pragma unroll
    for (int nf = 0; nf < 4; ++nf)
#pragma unroll
      for (int ks = 0; ks < 2; ++ks)
        bbf[nf][ks] = *(const bf16x8*)(B + (wr * 64 + nf * 16 + (lane & 15)) * 128 +
                                       ((ks * 64 + kcol) ^ rsw));
    __builtin_amdgcn_s_setprio(1);
#pragma unroll
    for (int ks = 0; ks < 2; ++ks)
#pragma unroll
      for (int mf = 0; mf < 4; ++mf)
#pragma unroll
        for (int nf = 0; nf < 4; ++nf)
          acc[mf][nf] = __builtin_amdgcn_mfma_f32_16x16x32_bf16(a[mf][ks], bbf[nf][ks],
                                                                acc[mf][nf], 0, 0, 0);
    __builtin_amdgcn_s_setprio(0);
  };

#define WAIT12 asm volatile("s_waitcnt vmcnt(12)" ::: "memory"); \
  __builtin_amdgcn_s_barrier(); asm volatile("" ::: "memory")

  // prologue (order matters for vmcnt counting: STB0, aA0, STB1)
  stageB(0, lds);
  loadA(aA, 0);
  stageB(1, lds + 32768);

  for (int tt = 0; tt < 12; tt += 4) {
    // tile tt+0: buf0, cur aA
    loadA(aB, tt + 1);
    WAIT12;
    stageB(tt + 2, lds + 2 * 32768);
    comp(lds, aA);
    // tile tt+1: buf1, cur aB
    loadA(aA, tt + 2);
    WAIT12;
    stageB(tt + 3, lds + 3 * 32768);
    comp(lds + 32768, aB);
    // tile tt+2: buf2, cur aA
    loadA(aB, tt + 3);
    WAIT12;
    stageB(tt + 4, lds);
    comp(lds + 2 * 32768, aA);
    // tile tt+3: buf3, cur aB
    loadA(aA, tt + 4);
    WAIT12;
    stageB(tt + 5, lds + 32768);
    comp(lds + 3 * 32768, aB);
  }
  // tail: tiles 12..15 (B(12)->buf0, B(13)->buf1 staged in last iteration)
  loadA(aB, 13);
  WAIT12;
  stageB(14, lds + 2 * 32768);
  comp(lds, aA);               // tile 12
  loadA(aA, 14);
  WAIT12;
  stageB(15, lds + 3 * 32768);
  comp(lds + 32768, aB);       // tile 13
  loadA(aB, 15);
  WAIT12;
  comp(lds + 2 * 32768, aA);   // tile 14
  asm volatile("s_waitcnt vmcnt(0)" ::: "memory");
  __builtin_amdgcn_s_barrier();
  asm volatile("" ::: "memory");
  comp(lds + 3 * 32768, aB);   // tile 15
#undef WAIT12

  // class-1000 dot extraction (cb7/wc1/mf2/lanegrp2/q0)
  if (cb == 7 && wc == 1 && ((lane >> 4) == 2)) {
#pragma unroll
    for (int nf = 0; nf < 4; ++nf) {
      int r = wr * 64 + nf * 16 + (lane & 15);
      pd[(size_t)rb * 256 + r] = acc[2][nf][0];
      acc[2][nf][0] = -1e30f;
    }
  }

  __syncthreads();
  float* mm = (float*)lds;
  float* zz = mm + 512;
  float* sv = zz + 512;
#pragma unroll
  for (int nf = 0; nf < 4; ++nf) {
    float m1 = -1e30f;
#pragma unroll
    for (int mf = 0; mf < 4; ++mf)
#pragma unroll
      for (int q = 0; q < 4; ++q) m1 = fmaxf(m1, acc[mf][nf][q]);
    m1 = fmaxf(m1, __shfl_xor(m1, 16));
    m1 = fmaxf(m1, __shfl_xor(m1, 32));
    float z1 = 0.f, s1 = 0.f;
#pragma unroll
    for (int mf = 0; mf < 4; ++mf)
#pragma unroll
      for (int q = 0; q < 4; ++q) {
        float tt2 = acc[mf][nf][q] - m1;
        float e = expf(tt2);
        z1 += e;
        s1 += e * tt2;
      }
    z1 += __shfl_xor(z1, 16); z1 += __shfl_xor(z1, 32);
    s1 += __shfl_xor(s1, 16); s1 += __shfl_xor(s1, 32);
    if (lane < 16) {
      int r = wr * 64 + nf * 16 + lane;
      mm[wc * 256 + r] = m1;
      zz[wc * 256 + r] = z1;
      sv[wc * 256 + r] = s1;
    }
  }
  __syncthreads();
  if (tid < 256) {
    float m0 = mm[tid], mA = mm[256 + tid];
    float z0 = zz[tid], zA = zz[256 + tid];
    float s0 = sv[tid], sA = sv[256 + tid];
    float M = fmaxf(m0, mA);
    float e0 = expf(m0 - M), e1 = expf(mA - M);
    float Z = z0 * e0 + zA * e1;
    float S = e0 * (s0 + (m0 - M) * z0) + e1 * (sA + (mA - M) * zA);
    size_t o = (size_t)cb * 8192 + R0 + tid;
    pm[o] = M;
    pz[o] = Z;
    ps[o] = S;
  }
}

// ---------------------------------------------------------------------------
// K4 slim (R18-proven): 32 blocks x 256 thr, one thread per row.
// ---------------------------------------------------------------------------
__global__ __launch_bounds__(256) void k4_final(const float* __restrict__ rnorm,
                                                const float* __restrict__ pm,
                                                const float* __restrict__ pz,
                                                const float* __restrict__ ps,
                                                const float* __restrict__ pd,
                                                float* __restrict__ out) {
  int row = blockIdx.x * 256 + threadIdx.x;
  float mv[8], zv[8], svv[8];
  float M = -1e30f;
#pragma unroll
  for (int c = 0; c < 8; ++c) {
    mv[c] = pm[(size_t)c * 8192 + row];
    zv[c] = pz[(size_t)c * 8192 + row];
    svv[c] = ps[(size_t)c * 8192 + row];
    M = fmaxf(M, mv[c]);
  }
  float Z = 0.f, S = 0.f;
#pragma unroll
  for (int c = 0; c < 8; ++c) {
    float e = expf(mv[c] - M);
    Z += zv[c] * e;
    S += e * (svv[c] + (mv[c] - M) * zv[c]);
  }
  float loss = S / Z - logf(Z);
  out[row] = loss * pd[row] * rnorm[row] * (1.f / 8192.f);
}

// ---------------------------------------------------------------------------
extern "C" void kernel_launch(void* const* d_in, const int* in_sizes, int n_in,
                              void* d_out, int out_size, void* d_ws, size_t ws_size,
                              hipStream_t stream) {
  (void)in_sizes; (void)n_in; (void)out_size; (void)ws_size;
  const float* x = (const float*)d_in[0];
  const float* W = (const float*)d_in[1];
  const float* b = (const float*)d_in[2];
  float* out = (float*)d_out;
  char* ws = (char*)d_ws;

  unsigned short* wtf = (unsigned short*)(ws + 0);          // 2 MiB frag-major
  unsigned short* xbf = (unsigned short*)(ws + 2097152);    // 16 MiB
  float* rnorm = (float*)(ws + 18874368);                   // 32 KiB
  float* s = (float*)(ws + 18907136);                       // 4 KiB
  float* sp = (float*)(ws + 18915328);                      // 1 MiB, aliases pm
  float* pm = (float*)(ws + 18915328);                      // 256 KiB
  float* pz = (float*)(ws + 18915328 + 262144);
  float* ps = (float*)(ws + 18915328 + 524288);
  float* pd = (float*)(ws + 18915328 + 786432);             // 32 KiB

  k01_prep<<<256, 1024, 0, stream>>>(W, wtf, x, xbf, rnorm, sp);
  k2_sred<<<16, 256, 0, stream>>>(sp, s, wtf);
  k3_gemm<<<256, 512, 0, stream>>>(xbf, wtf, b, pm, pz, ps, pd);
  k4_final<<<32, 256, 0, stream>>>(rnorm, pm, pz, ps, pd, out);
}